// Round 4
// baseline (7103.365 us; speedup 1.0000x reference)
//
#include <hip/hip_runtime.h>
#include <math.h>
#include <stdint.h>

// Dims
#define BN    256      // B*N
#define UVD   49       // U*V
#define STD_  64       // S*T
#define CHD   8
#define AD    98
#define MD    128
#define CD    16

#define ZSZ   (BN*AD*MD*CD)      // 51,380,224 elements
#define T2SZ  (BN*AD*STD_*CHD)   // 12,845,056
#define PVSZ  (AD*MD*CD)         // 200,704

typedef unsigned short u16;

// ---- bf16 helpers (internal storage bf16, compute fp32) ----
__device__ __forceinline__ float bflo(uint32_t u) {
    return __builtin_bit_cast(float, u << 16);
}
__device__ __forceinline__ float bfhi(uint32_t u) {
    return __builtin_bit_cast(float, u & 0xFFFF0000u);
}
__device__ __forceinline__ uint32_t packbf(float lo, float hi) {  // RNE pack 2 fp32 -> 2 bf16
    uint32_t a = __builtin_bit_cast(uint32_t, lo);
    uint32_t b = __builtin_bit_cast(uint32_t, hi);
    a = (a + 0x7FFFu + ((a >> 16) & 1u)) >> 16;
    b = (b + 0x7FFFu + ((b >> 16) & 1u)) >> 16;
    return a | (b << 16);
}

__device__ __forceinline__ void fma4(float4& a, const float4& v, float s) {
    a.x = fmaf(v.x, s, a.x); a.y = fmaf(v.y, s, a.y);
    a.z = fmaf(v.z, s, a.z); a.w = fmaf(v.w, s, a.w);
}

__device__ __forceinline__ uint32_t hsh(uint32_t x) {
    x ^= x >> 16; x *= 0x7feb352dU;
    x ^= x >> 15; x *= 0x846ca68bU;
    x ^= x >> 16; return x;
}

__device__ __forceinline__ float blockReduceSum256(float s) {
    __shared__ float sw[4];
    #pragma unroll
    for (int o = 32; o > 0; o >>= 1) s += __shfl_down(s, o, 64);
    int lane = threadIdx.x & 63, wi = threadIdx.x >> 6;
    if (lane == 0) sw[wi] = s;
    __syncthreads();
    return sw[0] + sw[1] + sw[2] + sw[3];
}

// ---------------- small prep: ds transpose ----------------

__global__ __launch_bounds__(256) void k_mkdst(const float* __restrict__ ds, float* __restrict__ dsT) {
    int i = blockIdx.x * 256 + threadIdx.x;   // i = st*128 + m
    if (i >= MD * STD_) return;
    int st = i >> 7, m = i & 127;
    dsT[i] = ds[m * STD_ + st];
}

// ---------------- power iteration support (fp32) ----------------

__global__ __launch_bounds__(256) void k_gram_a(const float* __restrict__ da, float* __restrict__ Ga) {
    int i = blockIdx.x * 256 + threadIdx.x;
    if (i >= AD * AD) return;
    int a = i / AD, b = i % AD;
    float s = 0.f;
    for (int uv = 0; uv < UVD; ++uv) s = fmaf(da[a * UVD + uv], da[b * UVD + uv], s);
    Ga[i] = s;
}

__global__ __launch_bounds__(256) void k_gram_s(const float* __restrict__ ds, float* __restrict__ Gs) {
    int i = blockIdx.x * 256 + threadIdx.x;
    if (i >= MD * MD) return;
    int m = i >> 7, n = i & 127;
    float s = 0.f;
    for (int st = 0; st < STD_; ++st) s = fmaf(ds[m * STD_ + st], ds[n * STD_ + st], s);
    Gs[i] = s;
}

__global__ __launch_bounds__(256) void k_gram_c(const float* __restrict__ dc, float* __restrict__ Gc) {
    int i = threadIdx.x;
    if (i >= CD * CD) return;
    int c = i >> 4, d = i & 15;
    float s = 0.f;
    for (int h = 0; h < CHD; ++h) s = fmaf(dc[c * CHD + h], dc[d * CHD + h], s);
    Gc[i] = s;
}

__global__ __launch_bounds__(256) void k_v0(float* __restrict__ v) {
    int i = blockIdx.x * 256 + threadIdx.x;
    if (i >= PVSZ) return;
    uint32_t h1 = hsh((uint32_t)(i * 2 + 1));
    uint32_t h2 = hsh((uint32_t)(i * 2 + 2) ^ 0x9e3779b9U);
    float u1 = ((float)h1 + 1.0f) * (1.0f / 4294967808.0f);   // (0,1)
    float u2 = (float)h2 * (1.0f / 4294967296.0f);
    v[i] = sqrtf(-2.f * logf(u1)) * cosf(6.28318530718f * u2);
}

__global__ __launch_bounds__(256) void k_ata1(const float* __restrict__ v, const float* __restrict__ Gc,
                                              float* __restrict__ w1) {
    int p = blockIdx.x * 256 + threadIdx.x;   // a*128+m
    if (p >= AD * MD) return;
    float vv[16];
    const float4* vp = (const float4*)(v + p * 16);
    #pragma unroll
    for (int j = 0; j < 4; ++j) {
        float4 t = vp[j];
        vv[4*j] = t.x; vv[4*j+1] = t.y; vv[4*j+2] = t.z; vv[4*j+3] = t.w;
    }
    float4* op = (float4*)(w1 + p * 16);
    #pragma unroll
    for (int j = 0; j < 4; ++j) {
        float o[4];
        #pragma unroll
        for (int k = 0; k < 4; ++k) {
            int d = 4*j + k;
            float s = 0.f;
            #pragma unroll
            for (int c = 0; c < 16; ++c) s = fmaf(vv[c], Gc[c * 16 + d], s);
            o[k] = s;
        }
        op[j] = make_float4(o[0], o[1], o[2], o[3]);
    }
}

__global__ __launch_bounds__(256) void k_ata2(const float* __restrict__ w1, const float* __restrict__ Gs,
                                              float* __restrict__ w2) {
    __shared__ float w1a[MD * CD];
    int a = blockIdx.x, t = threadIdx.x;
    for (int e = t; e < MD * CD; e += 256) w1a[e] = w1[a * MD * CD + e];
    __syncthreads();
    for (int o = t; o < MD * CD; o += 256) {
        int n = o >> 4, d = o & 15;
        float s = 0.f;
        for (int m = 0; m < MD; ++m) s = fmaf(w1a[m * 16 + d], Gs[m * 128 + n], s);
        w2[a * 2048 + o] = s;
    }
}

__global__ __launch_bounds__(256) void k_ata3(const float* __restrict__ w2, const float* __restrict__ Ga,
                                              float* __restrict__ wv) {
    __shared__ float w2n[AD * CD];
    __shared__ float gal[AD * AD];
    int n = blockIdx.x, t = threadIdx.x;
    for (int e = t; e < AD * CD; e += 256) {
        int a = e >> 4, d = e & 15;
        w2n[e] = w2[a * 2048 + n * 16 + d];
    }
    for (int e = t; e < AD * AD; e += 256) gal[e] = Ga[e];
    __syncthreads();
    for (int o = t; o < AD * CD; o += 256) {
        int b = o >> 4, d = o & 15;
        float s = 0.f;
        for (int a = 0; a < AD; ++a) s = fmaf(w2n[a * 16 + d], gal[a * 98 + b], s);
        wv[b * 2048 + n * 16 + d] = s;
    }
}

__global__ __launch_bounds__(256) void k_red1(const float* __restrict__ wv, float* __restrict__ part) {
    int i = blockIdx.x * 256 + threadIdx.x;   // grid exactly 784*256 = PVSZ
    float x = wv[i];
    float tot = blockReduceSum256(x * x);
    if (threadIdx.x == 0) part[blockIdx.x] = tot;
}

__global__ __launch_bounds__(256) void k_norm(const float* __restrict__ wv, const float* __restrict__ part,
                                              float* __restrict__ v) {
    int t = threadIdx.x;
    float s = 0.f;
    for (int i = t; i < 784; i += 256) s += part[i];
    float tot = blockReduceSum256(s);
    float nrm = sqrtf(tot);
    float sc = 1.f / (nrm + 1e-12f);
    int i = blockIdx.x * 256 + t;
    v[i] = wv[i] * sc;
}

__global__ __launch_bounds__(256) void k_L(const float* __restrict__ part, float* __restrict__ scal) {
    int t = threadIdx.x;
    float s = 0.f;
    for (int i = t; i < 784; i += 256) s += part[i];
    float tot = blockReduceSum256(s);
    if (t == 0) {
        float L = fmaxf(sqrtf(tot), 1e-6f);
        scal[1] = 1.f / L;      // step
        scal[2] = 0.1f / L;     // thr = COUPLE/L
    }
}

// ---------------- FISTA fused kernels ----------------

// Fused recon_a + adj_a, st-chunked (128 elems = 16 st x 8 h per chunk), in-place on t2 (bf16).
// FIRSTX: r = -x (recon(y0)=0). Else: r = sum_a t2[a,..]*da[a,uv] - x.
// Then t2[a,..] = sum_uv r[uv,..]*da[a,uv].
// NOTE: t2g/t2o intentionally NOT __restrict__ (same buffer, in-place per block).
template<int FIRSTX>
__global__ __launch_bounds__(256) void k_fusedA(const u16* t2g, const float* __restrict__ da,
                                                const float* __restrict__ xg, u16* t2o) {
    __shared__ float l_in[98 * 130];   // 50.96 KB
    __shared__ float l_r[49 * 132];    // 25.87 KB
    int ch = blockIdx.x, bn = blockIdx.y, t = threadIdx.x;
    int base = ch * 128;               // element offset within 512-row
    if (!FIRSTX) {
        for (int e8 = t; e8 < 1568; e8 += 256) {          // 98 a * 16 uint4 (8 bf16 each)
            int a = e8 >> 4, r8 = e8 & 15;
            uint4 v = *(const uint4*)&t2g[(size_t)(bn * 98 + a) * 512 + base + r8 * 8];
            float* d = &l_in[a * 130 + r8 * 8];
            d[0] = bflo(v.x); d[1] = bfhi(v.x); d[2] = bflo(v.y); d[3] = bfhi(v.y);
            d[4] = bflo(v.z); d[5] = bfhi(v.z); d[6] = bflo(v.w); d[7] = bfhi(v.w);
        }
        __syncthreads();
        for (int e2 = t; e2 < 3136; e2 += 256) {          // 49 uv * 64 pairs
            int uv = e2 >> 6, i2 = (e2 & 63) * 2;
            float s0 = 0.f, s1 = 0.f;
            for (int a = 0; a < 98; ++a) {
                float w = da[a * 49 + uv];                // wave-uniform
                s0 = fmaf(l_in[a * 130 + i2], w, s0);
                s1 = fmaf(l_in[a * 130 + i2 + 1], w, s1);
            }
            float2 xv = *(const float2*)&xg[(size_t)bn * 25088 + uv * 512 + base + i2];
            l_r[uv * 132 + i2]     = s0 - xv.x;
            l_r[uv * 132 + i2 + 1] = s1 - xv.y;
        }
    } else {
        for (int e2 = t; e2 < 3136; e2 += 256) {
            int uv = e2 >> 6, i2 = (e2 & 63) * 2;
            float2 xv = *(const float2*)&xg[(size_t)bn * 25088 + uv * 512 + base + i2];
            l_r[uv * 132 + i2]     = -xv.x;
            l_r[uv * 132 + i2 + 1] = -xv.y;
        }
    }
    __syncthreads();
    for (int e2 = t; e2 < 6272; e2 += 256) {              // 98 a * 64 pairs
        int a = e2 >> 6, i2 = (e2 & 63) * 2;
        float s0 = 0.f, s1 = 0.f;
        for (int uv = 0; uv < 49; ++uv) {
            float w = da[a * 49 + uv];                    // wave-uniform
            s0 = fmaf(l_r[uv * 132 + i2], w, s0);
            s1 = fmaf(l_r[uv * 132 + i2 + 1], w, s1);
        }
        *(uint32_t*)&t2o[(size_t)(bn * 98 + a) * 512 + base + i2] = packbf(s0, s1);
    }
}

// Fused adj_s + (x dc^T) + FISTA update + (x dc) + recon_s, per (bn,a) slice, in-place on t2.
// t2 in: (residual x_a da)[st,h].  Y/Z (bf16): y_{j-1}, z_{j-1} -> updated in place to y_j, z_j.
// t2 out: (y_j x dc x ds)[st,h]  (z_j instead if last).
__global__ __launch_bounds__(256) void k_fused(const u16* t2g, u16* t2o,
                                               const float* __restrict__ dsT, const float* __restrict__ ds,
                                               const float* __restrict__ dc, const float* __restrict__ scal,
                                               u16* __restrict__ Y, u16* __restrict__ Z,
                                               float beta, int first, int last) {
    __shared__ float l_dsT[8192];      // st-major: [st*128+m], 32 KB
    __shared__ float l_t2[512];
    __shared__ float l_t1b[128 * 9];   // padded stride 9
    __shared__ float l_po[128 * 18];   // partials: [m*18 + h*2 + half]
    __shared__ float l_dc[128];
    int p = blockIdx.x, t = threadIdx.x;

    // stage 0: loads
    for (int e = t; e < 2048; e += 256)
        *(float4*)&l_dsT[e * 4] = *(const float4*)&dsT[e * 4];
    if (t < 64) {
        uint4 v = *(const uint4*)&t2g[(size_t)p * 512 + t * 8];
        float* d = &l_t2[t * 8];
        d[0] = bflo(v.x); d[1] = bfhi(v.x); d[2] = bflo(v.y); d[3] = bfhi(v.y);
        d[4] = bflo(v.z); d[5] = bfhi(v.z); d[6] = bflo(v.w); d[7] = bfhi(v.w);
    }
    if (t < 128) l_dc[t] = dc[t];
    __syncthreads();

    // stage A: t1b[m,h] = sum_st t2[st,h] * ds[m,st]
    {
        int h = t & 7, mg = t >> 3;    // mg 0..31 -> 4 m's
        float4 acc = make_float4(0.f, 0.f, 0.f, 0.f);
        for (int st = 0; st < 64; ++st) {
            float v = l_t2[st * 8 + h];
            float4 d4 = *(const float4*)&l_dsT[st * 128 + mg * 4];
            fma4(acc, d4, v);
        }
        l_t1b[(mg * 4 + 0) * 9 + h] = acc.x;
        l_t1b[(mg * 4 + 1) * 9 + h] = acc.y;
        l_t1b[(mg * 4 + 2) * 9 + h] = acc.z;
        l_t1b[(mg * 4 + 3) * 9 + h] = acc.w;
    }
    __syncthreads();

    // stage B: g = t1b x dc^T ; FISTA pointwise ; o-partials = src x dc
    {
        int m = t >> 1, half = t & 1, c0 = half * 8;
        float tb[8];
        #pragma unroll
        for (int hh = 0; hh < 8; ++hh) tb[hh] = l_t1b[m * 9 + hh];
        float g[8];
        #pragma unroll
        for (int cc = 0; cc < 8; ++cc) {
            float s = 0.f;
            #pragma unroll
            for (int hh = 0; hh < 8; ++hh) s = fmaf(tb[hh], l_dc[(c0 + cc) * 8 + hh], s);
            g[cc] = s;
        }
        float step = scal[1], thr = scal[2];
        size_t q = (size_t)p * 2048 + t * 8;
        float yv[8], zv[8];
        if (!first) {
            uint4 a = *(const uint4*)&Y[q];
            yv[0] = bflo(a.x); yv[1] = bfhi(a.x); yv[2] = bflo(a.y); yv[3] = bfhi(a.y);
            yv[4] = bflo(a.z); yv[5] = bfhi(a.z); yv[6] = bflo(a.w); yv[7] = bfhi(a.w);
            uint4 b = *(const uint4*)&Z[q];
            zv[0] = bflo(b.x); zv[1] = bfhi(b.x); zv[2] = bflo(b.y); zv[3] = bfhi(b.y);
            zv[4] = bflo(b.z); zv[5] = bfhi(b.z); zv[6] = bflo(b.w); zv[7] = bfhi(b.w);
        } else {
            #pragma unroll
            for (int cc = 0; cc < 8; ++cc) { yv[cc] = 0.f; zv[cc] = 0.f; }
        }
        float zn[8], yn[8], src[8];
        #pragma unroll
        for (int cc = 0; cc < 8; ++cc) {
            float pv = fmaf(-step, g[cc], yv[cc]);
            float av = fabsf(pv) - thr;
            float z1 = (av > 0.f) ? copysignf(av, pv) : 0.f;
            zn[cc] = z1;
            yn[cc] = fmaf(beta, z1 - zv[cc], z1);
            src[cc] = last ? z1 : yn[cc];
        }
        if (!last) {
            uint4 oz, oy;
            oz.x = packbf(zn[0], zn[1]); oz.y = packbf(zn[2], zn[3]);
            oz.z = packbf(zn[4], zn[5]); oz.w = packbf(zn[6], zn[7]);
            *(uint4*)&Z[q] = oz;
            oy.x = packbf(yn[0], yn[1]); oy.y = packbf(yn[2], yn[3]);
            oy.z = packbf(yn[4], yn[5]); oy.w = packbf(yn[6], yn[7]);
            *(uint4*)&Y[q] = oy;
        }
        #pragma unroll
        for (int hh = 0; hh < 8; ++hh) {
            float s = 0.f;
            #pragma unroll
            for (int cc = 0; cc < 8; ++cc) s = fmaf(src[cc], l_dc[(c0 + cc) * 8 + hh], s);
            l_po[m * 18 + hh * 2 + half] = s;
        }
    }
    __syncthreads();

    // stage C: t2o[st,h] = sum_m o[m,h] * ds[m,st]
    {
        int e0 = 2 * t, st = e0 >> 3, h0 = e0 & 7;   // h0 even
        float a0 = 0.f, a1 = 0.f;
        for (int mm = 0; mm < 128; ++mm) {
            float w = ds[mm * 64 + st];              // global scalar, L1/L2-hot
            float s0 = l_po[mm * 18 + h0 * 2] + l_po[mm * 18 + h0 * 2 + 1];
            float s1 = l_po[mm * 18 + (h0 + 1) * 2] + l_po[mm * 18 + (h0 + 1) * 2 + 1];
            a0 = fmaf(s0, w, a0);
            a1 = fmaf(s1, w, a1);
        }
        *(uint32_t*)&t2o[(size_t)p * 512 + e0] = packbf(a0, a1);
    }
}

// Final angular recon: out[bn,uv,st,h] = sum_a t2[bn,a,st,h]*da[a,uv]  (fp32 out)
__global__ __launch_bounds__(128) void k_recon_out(const u16* __restrict__ t2, const float* __restrict__ da,
                                                   float* __restrict__ out) {
    __shared__ float lt2[16 * 512];
    int uvg = blockIdx.x, bn = blockIdx.y, t = threadIdx.x;
    float4 acc[7];
    #pragma unroll
    for (int u = 0; u < 7; ++u) acc[u] = make_float4(0.f, 0.f, 0.f, 0.f);
    for (int c0 = 0; c0 < AD; c0 += 16) {
        int na = min(16, AD - c0);
        for (int e8 = t; e8 < na * 64; e8 += 128) {
            uint4 v = *(const uint4*)&t2[(size_t)(bn * AD + c0) * 512 + e8 * 8];
            float* d = &lt2[e8 * 8];
            d[0] = bflo(v.x); d[1] = bfhi(v.x); d[2] = bflo(v.y); d[3] = bfhi(v.y);
            d[4] = bflo(v.z); d[5] = bfhi(v.z); d[6] = bflo(v.w); d[7] = bfhi(v.w);
        }
        __syncthreads();
        for (int al = 0; al < na; ++al) {
            float4 rv = *(const float4*)&lt2[al * 512 + t * 4];
            int a = c0 + al;
            #pragma unroll
            for (int u = 0; u < 7; ++u)
                fma4(acc[u], rv, da[a * 49 + uvg * 7 + u]);   // wave-uniform
        }
        __syncthreads();
    }
    #pragma unroll
    for (int u = 0; u < 7; ++u) {
        size_t idx = (size_t)bn * 25088 + (uvg * 7 + u) * 512 + t * 4;
        *(float4*)&out[idx] = acc[u];
    }
}

// ---------------- launcher ----------------

extern "C" void kernel_launch(void* const* d_in, const int* in_sizes, int n_in,
                              void* d_out, int out_size, void* d_ws, size_t ws_size,
                              hipStream_t stream) {
    const float* x  = (const float*)d_in[0];
    const float* da = (const float*)d_in[1];
    const float* ds = (const float*)d_in[2];
    const float* dc = (const float*)d_in[3];
    float* out = (float*)d_out;

    char* base = (char*)d_ws;
    u16* Y  = (u16*)base; base += (size_t)ZSZ * 2;    // 102.76 MB
    u16* Z  = (u16*)base; base += (size_t)ZSZ * 2;    // 102.76 MB
    u16* t2 = (u16*)base; base += (size_t)T2SZ * 2;   // 25.69 MB
    float* fb = (float*)base;
    size_t off = 0;
    float* dsT  = fb + off; off += MD * STD_;      // 8192
    float* Ga   = fb + off; off += AD * AD;        // 9604
    float* Gs   = fb + off; off += MD * MD;        // 16384
    float* Gc   = fb + off; off += CD * CD + 12;   // 256 (+pad to keep 16B align)
    float* v    = fb + off; off += PVSZ;
    float* w1   = fb + off; off += PVSZ;
    float* w2   = fb + off; off += PVSZ;
    float* wv   = fb + off; off += PVSZ;
    float* part = fb + off; off += 784;
    float* scal = fb + off; off += 4;
    (void)ws_size; (void)in_sizes; (void)n_in; (void)out_size;

    // ---- prep + power iteration for L (10 iters, as in reference) ----
    k_mkdst<<<32, 256, 0, stream>>>(ds, dsT);
    k_gram_a<<<(AD * AD + 255) / 256, 256, 0, stream>>>(da, Ga);
    k_gram_s<<<(MD * MD) / 256, 256, 0, stream>>>(ds, Gs);
    k_gram_c<<<1, 256, 0, stream>>>(dc, Gc);
    k_v0<<<784, 256, 0, stream>>>(v);
    for (int it = 0; it < 10; ++it) {
        k_ata1<<<49, 256, 0, stream>>>(v, Gc, w1);
        k_ata2<<<98, 256, 0, stream>>>(w1, Gs, w2);
        k_ata3<<<128, 256, 0, stream>>>(w2, Ga, wv);
        k_red1<<<784, 256, 0, stream>>>(wv, part);
        k_norm<<<784, 256, 0, stream>>>(wv, part, v);
    }
    k_L<<<1, 256, 0, stream>>>(part, scal);

    // ---- beta schedule (host, matches reference t-recurrence) ----
    float betaArr[16];
    betaArr[0] = 0.f;
    double tprev = 1.0;
    for (int j = 1; j <= 15; ++j) {
        double tn = (1.0 + sqrt(1.0 + 4.0 * tprev * tprev)) * 0.5;
        betaArr[j] = (float)((tprev - 1.0) / tn);
        tprev = tn;
    }

    // ---- FISTA: 15 iterations ----
    for (int j = 1; j <= 15; ++j) {
        if (j == 1) {
            k_fusedA<1><<<dim3(4, 256), 256, 0, stream>>>(t2, da, x, t2);
        } else {
            k_fusedA<0><<<dim3(4, 256), 256, 0, stream>>>(t2, da, x, t2);
        }
        k_fused<<<BN * AD, 256, 0, stream>>>(t2, t2, dsT, ds, dc, scal, Y, Z,
                                             betaArr[j], (j == 1) ? 1 : 0, (j == 15) ? 1 : 0);
    }

    // ---- final recon(z15) -> out (t2 already = z15 x dc x ds) ----
    k_recon_out<<<dim3(7, 256), 128, 0, stream>>>(t2, da, out);
}